// Round 9
// baseline (510.298 us; speedup 1.0000x reference)
//
#include <hip/hip_runtime.h>
#include <hip/hip_cooperative_groups.h>
#include <stdint.h>

namespace cg = cooperative_groups;

// Problem constants (from reference)
#define N_CLASSES  10
#define N_TREES    4000
#define DEPTH      6
#define N_INTERNAL 63
#define N_FEATURES 128
#define BATCH      32768
#define LR         0.1f

// Kernel config (R21 = R20 + pack fused into eval via cooperative grid sync).
// Counter evidence R20: (1) eval 243->250 from 4.07M LDS bank conflicts in
// the XT=false xs staging -- STRUCTURAL (gather needs bank==s, so the
// transposing write must same-bank); ~7us accepted, bought the 33MB
// transpose removal. (2) total-minus-eval ~= 38-47us across R15-R20
// regardless of prep size -> the SECOND DISPATCH costs ~40us, not the prep
// work. R21 removes it: one cooperative kernel = {xs stage + pack share} ->
// threadfence + grid.sync -> champion eval loop (byte-identical). Grid is
// exactly co-resident: 1024 blocks, 4/CU by LDS (34.3KB), VGPR 52.
// Launcher hedges: cooperative-launch error at capture -> two-kernel R20.
#define BLOCK       256
#define SAMPLES_PB  32
#define T_TILE      16                      // trees per LDS tile (8 KB int2 nodes)
#define N_TILES     (N_TREES / T_TILE)      // 250
#define TILES_PER_CLASS ((N_TREES / N_CLASSES) / T_TILE)   // 25
#define SUMS_STRIDE 11

// ws layout:
//   [0, 2.048MB)        nodes by slot, interleaved int2 (feat, thr_bits), 64/tree
//   [2.048MB, 3.072MB)  leaves (64 f32/tree), class-grouped slots
// slot = (t%10)*400 + t/10  (class-grouped: 25-tile runs are single-class).
#define WS_NODES_BYTES  ((size_t)N_TREES * 64 * 8)
#define WS_LEAVES_BYTES ((size_t)N_TREES * 64 * 4)

// s_waitcnt immediates (gfx9): vmcnt[3:0] | expcnt<<4 | lgkmcnt<<8
#define WAITCNT_VM4  0x0F74    // vmcnt(4): keep 4 newest (lv pair + next DMA pair)
#define WAITCNT_VM2  0x0F72    // vmcnt(2): keep 2 newest (lv pair), last tile

// CK-style addrspace casts for global_load_lds (proven R5..R12).
__device__ __forceinline__ void load_lds_16(const void* g, void* l) {
    const auto* g1 = reinterpret_cast<const __attribute__((address_space(1))) uint32_t*>(
        reinterpret_cast<uintptr_t>(g));
    auto* l3 = reinterpret_cast<__attribute__((address_space(3))) uint32_t*>(
        reinterpret_cast<uintptr_t>(l));
    __builtin_amdgcn_global_load_lds(g1, l3, 16, 0, 0);
}

// ---------- Fused cooperative kernel: pack + eval in one dispatch ----------
__global__ __launch_bounds__(BLOCK, 4) void gbt_fused(
    const float* __restrict__ x,          // [BATCH][F] row-major
    const int*   __restrict__ features,   // [N_TREES][63]
    const float* __restrict__ thresholds, // [N_TREES][63]
    const float* __restrict__ leaves,     // [N_TREES][64]
    const float* __restrict__ init_out,   // [10]
    float*       __restrict__ out,        // [BATCH][10]
    int2*        __restrict__ pnodes,     // ws: [N_TREES][64] int2, slot order
    float*       __restrict__ pleaves)    // ws: [N_TREES][64], slot order
{
    __shared__ float xs[N_FEATURES * SAMPLES_PB];       // 16 KB, transposed [f][s]
    __shared__ int2  nbuf[2][T_TILE * 64];              // 2 x 8 KB node tiles
    __shared__ float sums[SAMPLES_PB * SUMS_STRIDE];    // 1.4 KB

    const int tid = threadIdx.x;
    const int sample0 = blockIdx.x * SAMPLES_PB;
    const int lane    = tid & 63;
    const int wv      = tid >> 6;       // wave id 0..3 (wave-uniform)

    // ---- Phase 0a (block-local): stage xs from row-major x ----
    // 32-way bank conflict on the transposing stores is structural (gather
    // layout needs bank==s); ~7us total, accepted (R20 counter evidence).
    {
        const float4* xg = (const float4*)(x + (size_t)sample0 * N_FEATURES);
        for (int e = tid; e < SAMPLES_PB * (N_FEATURES / 4); e += BLOCK) {
            int s = e >> 5, f4 = e & 31;
            float4 v = xg[e];
            int f = f4 << 2;
            xs[(f + 0) * SAMPLES_PB + s] = v.x;
            xs[(f + 1) * SAMPLES_PB + s] = v.y;
            xs[(f + 2) * SAMPLES_PB + s] = v.z;
            xs[(f + 3) * SAMPLES_PB + s] = v.w;
        }
    }
    for (int i = tid; i < SAMPLES_PB * SUMS_STRIDE; i += BLOCK) sums[i] = 0.f;

    // ---- Phase 0b (grid-cooperative): pack this thread's share ----
    // 256000 elements over 262144 threads: one (tree,node) each.
    {
        int i = blockIdx.x * BLOCK + tid;
        int t = i >> 6, n = i & 63;
        if (t < N_TREES) {
            int slot = (t % N_CLASSES) * (N_TREES / N_CLASSES) + (t / N_CLASSES);
            if (n < N_INTERNAL)
                pnodes[slot * 64 + n] =
                    make_int2(features[t * N_INTERNAL + n],
                              __float_as_int(thresholds[t * N_INTERNAL + n]));
            pleaves[slot * 64 + n] = leaves[t * 64 + n];
        }
    }

    // Device-scope visibility of pack stores (per-XCD L2s not coherent),
    // then grid-wide barrier: every block's ws share is complete.
    __threadfence();
    cg::this_grid().sync();

    // ---- Phase 1: champion eval loop (byte-identical to R13/R20) ----
    auto stage = [&](int tile, int b) {
        const char* g = (const char*)(pnodes + (size_t)(tile * T_TILE) * 64);
        char* lbase = (char*)&nbuf[b][0];
        #pragma unroll
        for (int q = 0; q < 2; ++q) {
            int k = wv * 2 + q;
            load_lds_16(g + k * 1024 + lane * 16, lbase + k * 1024);
        }
    };

    stage(0, 0);
    __syncthreads();   // xs cross-wave sharing + drains stage(0) vmcnt

    const int sLocal = tid & (SAMPLES_PB - 1);
    const int j      = tid >> 5;        // 0..7 half-wave chunks; trees 2j, 2j+1

    int cur = 0;
    for (int c = 0; c < N_CLASSES; ++c) {
        float acc = 0.f;
        float lv0 = 0.f, lv1 = 0.f;     // previous tile's leaf loads (pipelined)
        for (int t25 = 0; t25 < TILES_PER_CLASS; ++t25) {
            const int tile = c * TILES_PER_CLASS + t25;
            // Issue next-tile DMA, then wait for THIS tile's DMA only:
            // vmcnt(4) keeps {lv pair, next DMA pair} in flight (FIFO order:
            // DMA(t) < lv(t-1) < DMA(t+1)).
            if (tile + 1 < N_TILES) {
                stage(tile + 1, cur ^ 1);
                __builtin_amdgcn_s_waitcnt(WAITCNT_VM4);
            } else {
                __builtin_amdgcn_s_waitcnt(WAITCNT_VM2);
            }

            const int2* nb0 = &nbuf[cur][(j * 2 + 0) * 64];
            const int2* nb1 = &nbuf[cur][(j * 2 + 1) * 64];
            int o0 = 0, o1 = 0;
            #pragma unroll
            for (int d = 0; d < DEPTH; ++d) {
                int2 a = nb0[o0];           // ds_read_b64 (interleaved f,thr)
                int2 b = nb1[o1];
                float x0 = xs[a.x * SAMPLES_PB + sLocal];
                float x1 = xs[b.x * SAMPLES_PB + sLocal];
                o0 = 2 * o0 + 1 + (x0 > __int_as_float(a.y) ? 1 : 0);
                o1 = 2 * o1 + 1 + (x1 > __int_as_float(b.y) ? 1 : 0);
            }
            const size_t slotA = (size_t)(tile * T_TILE + j * 2);
            // Consume PREVIOUS tile's leaves (older than DMA(t+1): this wait
            // never drains the prefetch), then issue this tile's leaf loads.
            acc += lv0 + lv1;
            lv0 = pleaves[slotA * 64       + (o0 - N_INTERNAL)];
            lv1 = pleaves[(slotA + 1) * 64 + (o1 - N_INTERNAL)];
            cur ^= 1;
        }
        acc += lv0 + lv1;               // flush the class's final pair
        atomicAdd(&sums[sLocal * SUMS_STRIDE + c], acc);
    }
    __syncthreads();

    // Sole owner of these samples: plain coalesced stores, init folded in.
    for (int e = tid; e < SAMPLES_PB * N_CLASSES; e += BLOCK) {
        int s = e / N_CLASSES, k = e - s * N_CLASSES;
        out[(size_t)(sample0 + s) * N_CLASSES + k] =
            init_out[k] + LR * sums[s * SUMS_STRIDE + k];
    }
}

// ---------- Two-kernel fallback path (R20, proven 293us) ----------
__global__ void pack_kernel(const int* __restrict__ features,
                            const float* __restrict__ thresholds,
                            const float* __restrict__ leaves,
                            int2* __restrict__ pn, float* __restrict__ pl) {
    int i = blockIdx.x * blockDim.x + threadIdx.x;
    int t = i >> 6, n = i & 63;
    if (t < N_TREES) {
        int slot = (t % N_CLASSES) * (N_TREES / N_CLASSES) + (t / N_CLASSES);
        if (n < N_INTERNAL)
            pn[slot * 64 + n] = make_int2(features[t * N_INTERNAL + n],
                                          __float_as_int(thresholds[t * N_INTERNAL + n]));
        pl[slot * 64 + n] = leaves[t * 64 + n];
    }
}

__global__ __launch_bounds__(BLOCK, 4) void gbt_eval(
    const float* __restrict__ x,
    const int2*  __restrict__ pnodes,
    const float* __restrict__ pleaves,
    const float* __restrict__ init_out,
    float*       __restrict__ out)
{
    __shared__ float xs[N_FEATURES * SAMPLES_PB];
    __shared__ int2  nbuf[2][T_TILE * 64];
    __shared__ float sums[SAMPLES_PB * SUMS_STRIDE];

    const int tid = threadIdx.x;
    const int sample0 = blockIdx.x * SAMPLES_PB;
    const int lane    = tid & 63;
    const int wv      = tid >> 6;

    {
        const float4* xg = (const float4*)(x + (size_t)sample0 * N_FEATURES);
        for (int e = tid; e < SAMPLES_PB * (N_FEATURES / 4); e += BLOCK) {
            int s = e >> 5, f4 = e & 31;
            float4 v = xg[e];
            int f = f4 << 2;
            xs[(f + 0) * SAMPLES_PB + s] = v.x;
            xs[(f + 1) * SAMPLES_PB + s] = v.y;
            xs[(f + 2) * SAMPLES_PB + s] = v.z;
            xs[(f + 3) * SAMPLES_PB + s] = v.w;
        }
    }
    for (int i = tid; i < SAMPLES_PB * SUMS_STRIDE; i += BLOCK) sums[i] = 0.f;

    auto stage = [&](int tile, int b) {
        const char* g = (const char*)(pnodes + (size_t)(tile * T_TILE) * 64);
        char* lbase = (char*)&nbuf[b][0];
        #pragma unroll
        for (int q = 0; q < 2; ++q) {
            int k = wv * 2 + q;
            load_lds_16(g + k * 1024 + lane * 16, lbase + k * 1024);
        }
    };

    stage(0, 0);
    __syncthreads();

    const int sLocal = tid & (SAMPLES_PB - 1);
    const int j      = tid >> 5;

    int cur = 0;
    for (int c = 0; c < N_CLASSES; ++c) {
        float acc = 0.f;
        float lv0 = 0.f, lv1 = 0.f;
        for (int t25 = 0; t25 < TILES_PER_CLASS; ++t25) {
            const int tile = c * TILES_PER_CLASS + t25;
            if (tile + 1 < N_TILES) {
                stage(tile + 1, cur ^ 1);
                __builtin_amdgcn_s_waitcnt(WAITCNT_VM4);
            } else {
                __builtin_amdgcn_s_waitcnt(WAITCNT_VM2);
            }
            const int2* nb0 = &nbuf[cur][(j * 2 + 0) * 64];
            const int2* nb1 = &nbuf[cur][(j * 2 + 1) * 64];
            int o0 = 0, o1 = 0;
            #pragma unroll
            for (int d = 0; d < DEPTH; ++d) {
                int2 a = nb0[o0];
                int2 b = nb1[o1];
                float x0 = xs[a.x * SAMPLES_PB + sLocal];
                float x1 = xs[b.x * SAMPLES_PB + sLocal];
                o0 = 2 * o0 + 1 + (x0 > __int_as_float(a.y) ? 1 : 0);
                o1 = 2 * o1 + 1 + (x1 > __int_as_float(b.y) ? 1 : 0);
            }
            const size_t slotA = (size_t)(tile * T_TILE + j * 2);
            acc += lv0 + lv1;
            lv0 = pleaves[slotA * 64       + (o0 - N_INTERNAL)];
            lv1 = pleaves[(slotA + 1) * 64 + (o1 - N_INTERNAL)];
            cur ^= 1;
        }
        acc += lv0 + lv1;
        atomicAdd(&sums[sLocal * SUMS_STRIDE + c], acc);
    }
    __syncthreads();

    for (int e = tid; e < SAMPLES_PB * N_CLASSES; e += BLOCK) {
        int s = e / N_CLASSES, k = e - s * N_CLASSES;
        out[(size_t)(sample0 + s) * N_CLASSES + k] =
            init_out[k] + LR * sums[s * SUMS_STRIDE + k];
    }
}

// Fallback (ws too small for pack): direct-global gather.
__global__ __launch_bounds__(BLOCK, 8) void gbt_eval_global(
    const float* __restrict__ x,
    const int*   __restrict__ features,
    const float* __restrict__ thresholds,
    const float* __restrict__ leaf_values,
    const float* __restrict__ init_out,
    float*       __restrict__ out)
{
    __shared__ float xs[N_FEATURES * SAMPLES_PB];
    __shared__ float sums[SAMPLES_PB * N_CLASSES];
    const int tid = threadIdx.x;
    const int sample0 = blockIdx.x * SAMPLES_PB;
    {
        const float4* xg = (const float4*)(x + (size_t)sample0 * N_FEATURES);
        for (int e = tid; e < SAMPLES_PB * (N_FEATURES / 4); e += BLOCK) {
            int s = e >> 5, f4 = e & 31;
            float4 v = xg[e];
            int f = f4 << 2;
            xs[(f + 0) * SAMPLES_PB + s] = v.x;
            xs[(f + 1) * SAMPLES_PB + s] = v.y;
            xs[(f + 2) * SAMPLES_PB + s] = v.z;
            xs[(f + 3) * SAMPLES_PB + s] = v.w;
        }
    }
    for (int i = tid; i < SAMPLES_PB * N_CLASSES; i += BLOCK) sums[i] = 0.f;
    __syncthreads();
    const int sLocal = tid & (SAMPLES_PB - 1);
    const int j = tid >> 5;
    const int TPT = N_TREES / 8;
    const int t0 = j * TPT;
    float acc[N_CLASSES];
    #pragma unroll
    for (int k = 0; k < N_CLASSES; ++k) acc[k] = 0.f;
    for (int i = 0; i < TPT; i += N_CLASSES) {
        const int tt = t0 + i;
        int idx[N_CLASSES];
        #pragma unroll
        for (int u = 0; u < N_CLASSES; ++u) idx[u] = 0;
        #pragma unroll
        for (int d = 0; d < DEPTH; ++d) {
            #pragma unroll
            for (int u = 0; u < N_CLASSES; ++u) {
                int base = (tt + u) * N_INTERNAL + idx[u];
                float xv = xs[features[base] * SAMPLES_PB + sLocal];
                idx[u] = 2 * idx[u] + 1 + (xv > thresholds[base] ? 1 : 0);
            }
        }
        #pragma unroll
        for (int u = 0; u < N_CLASSES; ++u)
            acc[u] += leaf_values[(size_t)(tt + u) * 64 + idx[u] - N_INTERNAL];
    }
    #pragma unroll
    for (int k = 0; k < N_CLASSES; ++k)
        atomicAdd(&sums[sLocal * N_CLASSES + k], acc[k]);
    __syncthreads();
    for (int e = tid; e < SAMPLES_PB * N_CLASSES; e += BLOCK) {
        int s = e / N_CLASSES, k = e - s * N_CLASSES;
        out[(size_t)(sample0 + s) * N_CLASSES + k] = init_out[k] + LR * sums[e];
    }
}

extern "C" void kernel_launch(void* const* d_in, const int* in_sizes, int n_in,
                              void* d_out, int out_size, void* d_ws, size_t ws_size,
                              hipStream_t stream) {
    const float* x          = (const float*)d_in[0];
    const int*   features   = (const int*)d_in[1];
    const float* thresholds = (const float*)d_in[2];
    const float* leafvals   = (const float*)d_in[3];
    const float* init_out   = (const float*)d_in[4];
    float*       out        = (float*)d_out;

    const int grid = BATCH / SAMPLES_PB;    // 1024 = 256 CU x 4 blocks

    if (ws_size >= WS_NODES_BYTES + WS_LEAVES_BYTES) {
        int2*  pn = (int2*)d_ws;
        float* pl = (float*)((char*)d_ws + WS_NODES_BYTES);

        // Single cooperative dispatch (saves the ~40us second-kernel gap).
        void* args[] = {(void*)&x, (void*)&features, (void*)&thresholds,
                        (void*)&leafvals, (void*)&init_out, (void*)&out,
                        (void*)&pn, (void*)&pl};
        hipError_t err = hipLaunchCooperativeKernel(
            (const void*)gbt_fused, dim3(grid), dim3(BLOCK), args, 0, stream);
        if (err != hipSuccess) {
            // Capture-time failure -> proven two-kernel path (R20).
            int n = N_TREES * 64;
            pack_kernel<<<(n + 255) / 256, 256, 0, stream>>>(
                features, thresholds, leafvals, pn, pl);
            gbt_eval<<<grid, BLOCK, 0, stream>>>(x, pn, pl, init_out, out);
        }
    } else {
        gbt_eval_global<<<BATCH / SAMPLES_PB, BLOCK, 0, stream>>>(
            x, features, thresholds, leafvals, init_out, out);
    }
}